// Round 5
// baseline (26.252 us; speedup 1.0000x reference)
//
#include <hip/hip_runtime.h>

// out[b,o] = min_i max(x[b,i], w[i,o])  (forward value of the STE expression)
// x: [4096][256] f32, w: [256][256] f32, out: [4096][256] f32.
//
// Zero LDS in the hot loop. Wave-uniform x rides the SCALAR pipe
// (s_load_dwordx16 from a pre-packed f16 layout; SGPR is src0 of v_pk_max),
// per-lane w rides VMEM (global_load_dwordx4, 128 KB packed layout; each
// block re-reads only 32 KB -> L1-resident). Compute: v_pk_max_f16 +
// v_pk_min_f16 = 2 ops/instr, f16 pairs along the reduction dim.
// Wave = 4 rows x 64 cols (lane = col). 1024 blocks x 256 thr = 4 blocks/CU,
// 4 waves/SIMD. 32 K-chunks (8 i each), depth-1 double-buffered prefetch;
// waitcnt ordering enforced with sched_barrier(0) (guide rule #18).
//
// Workspace: xt (f16 x, [r4 1024][c 32][rr 4][j 4] u32-pairs, 2 MB) at ws+0,
// wq (f16 w, [c 32][col 256][j 4] u32-pairs, 128 KB) at ws+2MB.

typedef _Float16 h2 __attribute__((ext_vector_type(2)));
typedef int i16v __attribute__((ext_vector_type(16)));

static __device__ __forceinline__ h2 pmin(h2 a, h2 b) {
    return __builtin_elementwise_min(a, b);
}

// ---------------- pre-pass: f32 -> packed f16 pair layouts ----------------
__global__ __launch_bounds__(256)
void prepack_kernel(const float* __restrict__ x, const float* __restrict__ w,
                    unsigned int* __restrict__ xt, unsigned int* __restrict__ wq) {
    const int tid = blockIdx.x * 256 + threadIdx.x;
    if (tid < 524288) {
        // xt flat = ((r4*32 + c)*16 + rr*4 + j); holds x[4r4+rr][8c+2j .. +1]
        const int j  = tid & 3;
        const int rr = (tid >> 2) & 3;
        const int c  = (tid >> 4) & 31;
        const int r4 = tid >> 9;
        const int row = (r4 << 2) + rr;
        const float2 v = *reinterpret_cast<const float2*>(&x[(size_t)row * 256 + (c << 3) + (j << 1)]);
        const h2 p = h2{(_Float16)v.x, (_Float16)v.y};
        xt[tid] = __builtin_bit_cast(unsigned int, p);
    } else {
        // wq[(c*256+col)*4 + j] = {w[8c+2j][col], w[8c+2j+1][col]}
        const int u   = tid - 524288;          // u = c*1024 + j*256 + col
        const int col = u & 255;
        const int j   = (u >> 8) & 3;
        const int c   = u >> 10;
        const int i0  = (c << 3) + (j << 1);
        const h2 p = h2{(_Float16)w[(size_t)i0 * 256 + col], (_Float16)w[(size_t)(i0 + 1) * 256 + col]};
        wq[(size_t)((((c << 8) + col) << 2) + j)] = __builtin_bit_cast(unsigned int, p);
    }
}

// ---------------- main kernel ----------------
#define PKSTEP(XS, WV, ACC) do { int _t;                                     \
    asm("v_pk_max_f16 %0, %1, %2" : "=v"(_t) : "s"(XS), "v"(WV));            \
    ACC = pmin(ACC, __builtin_bit_cast(h2, _t)); } while (0)

#define STEP16(Xv, Wv) do {                                                                                  \
    PKSTEP(Xv[0],  Wv.x, acc0); PKSTEP(Xv[1],  Wv.y, acc0); PKSTEP(Xv[2],  Wv.z, acc0); PKSTEP(Xv[3],  Wv.w, acc0); \
    PKSTEP(Xv[4],  Wv.x, acc1); PKSTEP(Xv[5],  Wv.y, acc1); PKSTEP(Xv[6],  Wv.z, acc1); PKSTEP(Xv[7],  Wv.w, acc1); \
    PKSTEP(Xv[8],  Wv.x, acc2); PKSTEP(Xv[9],  Wv.y, acc2); PKSTEP(Xv[10], Wv.z, acc2); PKSTEP(Xv[11], Wv.w, acc2); \
    PKSTEP(Xv[12], Wv.x, acc3); PKSTEP(Xv[13], Wv.y, acc3); PKSTEP(Xv[14], Wv.z, acc3); PKSTEP(Xv[15], Wv.w, acc3); \
} while (0)

#define WAITALL() do {                                                       \
    asm volatile("s_waitcnt lgkmcnt(0) vmcnt(0)" ::: "memory");              \
    __builtin_amdgcn_sched_barrier(0); } while (0)

#define PF_X(DST, ADDR) asm volatile("s_load_dwordx16 %0, %1, 0x0" : "=s"(DST) : "s"(ADDR))
#define PF_W(DST, OFF)  asm volatile("global_load_dwordx4 %0, %1, %2" : "=v"(DST) : "v"(OFF), "s"(wb))

__global__ __launch_bounds__(256, 4)
void stemm_main(const unsigned int* __restrict__ xt, const unsigned int* __restrict__ wq,
                float* __restrict__ out) {
    const int t    = threadIdx.x;
    const int lane = t & 63;
    const int wv   = __builtin_amdgcn_readfirstlane(t >> 6);   // wave id 0..3, uniform
    const int c0   = (blockIdx.x & 3) << 6;                    // col group
    const int rb   = blockIdx.x >> 2;                          // row block (16 rows)
    const int r4   = (rb << 2) + wv;                           // row quad, uniform

    unsigned long long xa = (unsigned long long)xt + ((unsigned long long)r4 << 11); // r4*2048 B
    unsigned int       wo = (unsigned int)((c0 + lane) << 4);                        // col*16 B
    const unsigned long long wb = (unsigned long long)wq;

    i16v X0{}, X1{};
    uint4 W0{0, 0, 0, 0}, W1{0, 0, 0, 0};

    // prologue: chunk 0 -> buf0
    PF_X(X0, xa); PF_W(W0, wo);
    unsigned long long xan = xa + 64;
    unsigned int       won = wo + 4096;

    h2 acc0 = h2{(_Float16)65504.0f, (_Float16)65504.0f};
    h2 acc1 = acc0, acc2 = acc0, acc3 = acc0;

#pragma unroll 1
    for (int cc = 0; cc < 15; ++cc) {
        WAITALL();                                   // buf0 ready
        PF_X(X1, xan); PF_W(W1, won);                // chunk 2cc+1 -> buf1
        xan += 64; won += 4096;
        STEP16(X0, W0);
        WAITALL();                                   // buf1 ready
        PF_X(X0, xan); PF_W(W0, won);                // chunk 2cc+2 -> buf0
        xan += 64; won += 4096;
        STEP16(X1, W1);
    }
    WAITALL();                                       // chunk 30 ready
    PF_X(X1, xan); PF_W(W1, won);                    // chunk 31 -> buf1
    STEP16(X0, W0);
    WAITALL();                                       // chunk 31 ready
    STEP16(X1, W1);

    const int r0 = r4 << 2;
    out[(size_t)(r0 + 0) * 256 + c0 + lane] = fminf((float)acc0.x, (float)acc0.y);
    out[(size_t)(r0 + 1) * 256 + c0 + lane] = fminf((float)acc1.x, (float)acc1.y);
    out[(size_t)(r0 + 2) * 256 + c0 + lane] = fminf((float)acc2.x, (float)acc2.y);
    out[(size_t)(r0 + 3) * 256 + c0 + lane] = fminf((float)acc3.x, (float)acc3.y);
}

extern "C" void kernel_launch(void* const* d_in, const int* in_sizes, int n_in,
                              void* d_out, int out_size, void* d_ws, size_t ws_size,
                              hipStream_t stream) {
    const float* x = (const float*)d_in[0];
    const float* w = (const float*)d_in[1];
    float* out = (float*)d_out;

    unsigned int* xt = (unsigned int*)d_ws;                          // 2 MB
    unsigned int* wq = (unsigned int*)((char*)d_ws + (2u << 20));    // 128 KB

    hipLaunchKernelGGL(prepack_kernel, dim3(2176), dim3(256), 0, stream, x, w, xt, wq);
    hipLaunchKernelGGL(stemm_main, dim3(1024), dim3(256), 0, stream, xt, wq, out);
}

// Round 7
// 21.405 us; speedup vs baseline: 1.2265x; 1.2265x over previous
//
#include <hip/hip_runtime.h>

// out[b,o] = min_i max(x[b,i], w[i,o])  (forward value of the STE expression)
// x: [4096][256] f32, w: [256][256] f32, out: [4096][256] f32.
//
// Zero LDS. Wave-uniform x rides the SCALAR pipe (s_load_dwordx16 from a
// pre-packed f16 layout; SGPR is src0 of v_pk_max_f16). Per-lane w rides
// VMEM (global_load_dwordx4). Compute: fused v_pk_max_f16 + v_pk_min_f16.
// Wave = 4 rows x 64 cols. 1024 blocks x 256 thr = 4 blocks/CU, 4 waves/SIMD.
//
// R7 vs R6: wq re-laid out per-superchunk (8 contiguous dwords/col) so the
// two W loads use offset:0 / offset:16 (13-bit signed limit); early-clobber
// asm outputs so dests can't alias address regs.
//
// Workspace: xt (f16 x, [r4 1024][c 32][rr 4][j 4] u32-pairs, 2 MB) at ws+0,
// wq (f16 w, [sc 16][col 256][jj 8] u32-pairs, 128 KB) at ws+2MB.

typedef _Float16 h2 __attribute__((ext_vector_type(2)));
typedef int i16v __attribute__((ext_vector_type(16)));

// ---------------- pre-pass: f32 -> packed f16 pair layouts ----------------
__global__ __launch_bounds__(256)
void prepack_kernel(const float* __restrict__ x, const float* __restrict__ w,
                    unsigned int* __restrict__ xt, unsigned int* __restrict__ wq) {
    const int tid = blockIdx.x * 256 + threadIdx.x;
    if (tid < 524288) {
        // xt flat = ((r4*32 + c)*16 + rr*4 + j); holds x[4r4+rr][8c+2j .. +1]
        const int j  = tid & 3;
        const int rr = (tid >> 2) & 3;
        const int c  = (tid >> 4) & 31;
        const int r4 = tid >> 9;
        const int row = (r4 << 2) + rr;
        const float2 v = *reinterpret_cast<const float2*>(&x[(size_t)row * 256 + (c << 3) + (j << 1)]);
        const h2 p = h2{(_Float16)v.x, (_Float16)v.y};
        xt[tid] = __builtin_bit_cast(unsigned int, p);
    } else {
        // wq[((c>>1)*256 + col)*8 + (c&1)*4 + j] = {w[8c+2j][col], w[8c+2j+1][col]}
        const int u   = tid - 524288;          // u = c*1024 + j*256 + col
        const int col = u & 255;
        const int j   = (u >> 8) & 3;
        const int c   = u >> 10;
        const int i0  = (c << 3) + (j << 1);
        const h2 p = h2{(_Float16)w[(size_t)i0 * 256 + col], (_Float16)w[(size_t)(i0 + 1) * 256 + col]};
        const int idx = ((((c >> 1) << 8) + col) << 3) + ((c & 1) << 2) + j;
        wq[(size_t)idx] = __builtin_bit_cast(unsigned int, p);
    }
}

// ---------------- main kernel ----------------
// fused pmax+pmin in one asm block: SGPR src0, no mov churn.
#define PKSTEP(XS, WV, ACC) do { int _t;                                     \
    asm("v_pk_max_f16 %0, %2, %3\n\t"                                        \
        "v_pk_min_f16 %1, %1, %0"                                            \
        : "=&v"(_t), "+v"(ACC) : "s"(XS), "v"(WV)); } while (0)

// one 8-i chunk: X = 16 SGPRs [rr][j], W = 4 dwords [j]; same-acc dist = 8
#define STEPC(Xv, Wv) do {                                                   \
    PKSTEP(Xv[0],  Wv.x, acc0); PKSTEP(Xv[4],  Wv.x, acc1);                  \
    PKSTEP(Xv[8],  Wv.x, acc2); PKSTEP(Xv[12], Wv.x, acc3);                  \
    PKSTEP(Xv[1],  Wv.y, acc0); PKSTEP(Xv[5],  Wv.y, acc1);                  \
    PKSTEP(Xv[9],  Wv.y, acc2); PKSTEP(Xv[13], Wv.y, acc3);                  \
    PKSTEP(Xv[2],  Wv.z, acc0); PKSTEP(Xv[6],  Wv.z, acc1);                  \
    PKSTEP(Xv[10], Wv.z, acc2); PKSTEP(Xv[14], Wv.z, acc3);                  \
    PKSTEP(Xv[3],  Wv.w, acc0); PKSTEP(Xv[7],  Wv.w, acc1);                  \
    PKSTEP(Xv[11], Wv.w, acc2); PKSTEP(Xv[15], Wv.w, acc3); } while (0)

#define WAITALL() do {                                                       \
    asm volatile("s_waitcnt lgkmcnt(0) vmcnt(0)" ::: "memory");              \
    __builtin_amdgcn_sched_barrier(0); } while (0)

// prefetch one superchunk (16 i): 2 s_load_dwordx16 + 2 global_load_dwordx4.
// W: 8 contiguous dwords per col per sc -> offsets 0 and 16 (13-bit ok).
#define PF_SC(XA_, XB_, WA_, WB_, SC) do {                                   \
    const unsigned long long _xs = xa + (unsigned long long)(((SC) & 15) << 7); \
    const unsigned int _wo = wo + (unsigned int)(((SC) & 15) << 13);         \
    asm volatile("s_load_dwordx16 %0, %2, 0x0\n\t"                           \
                 "s_load_dwordx16 %1, %2, 0x40"                              \
                 : "=&s"(XA_), "=&s"(XB_) : "s"(_xs));                       \
    asm volatile("global_load_dwordx4 %0, %2, %3\n\t"                        \
                 "global_load_dwordx4 %1, %2, %3 offset:16"                  \
                 : "=&v"(WA_), "=&v"(WB_) : "v"(_wo), "s"(wb)); } while (0)

#define STAGE(K, CXA, CXB, CWA, CWB, NXA, NXB, NWA, NWB)                     \
    WAITALL();                                                               \
    if ((K) < 15) PF_SC(NXA, NXB, NWA, NWB, s0 + (K) + 1);                   \
    STEPC(CXA, CWA); STEPC(CXB, CWB);

__global__ __launch_bounds__(256, 4)
void stemm_main(const unsigned int* __restrict__ xt, const unsigned int* __restrict__ wq,
                float* __restrict__ out) {
    const int t    = threadIdx.x;
    const int lane = t & 63;
    const int wv   = __builtin_amdgcn_readfirstlane(t >> 6);   // wave id 0..3, uniform
    const int c0   = (blockIdx.x & 3) << 6;                    // col group
    const int rb   = blockIdx.x >> 2;                          // row block (16 rows)
    const int r4   = (rb << 2) + wv;                           // row quad, uniform
    const int s0   = wv << 2;                                  // phase stagger

    const unsigned long long xa = (unsigned long long)xt + ((unsigned long long)r4 << 11);
    const unsigned int       wo = (unsigned int)((c0 + lane) << 5);   // col*32 B
    const unsigned long long wb = (unsigned long long)wq;

    i16v X0a{}, X0b{}, X1a{}, X1b{};
    uint4 W0a{0,0,0,0}, W0b{0,0,0,0}, W1a{0,0,0,0}, W1b{0,0,0,0};

    h2 acc0 = h2{(_Float16)65504.0f, (_Float16)65504.0f};
    h2 acc1 = acc0, acc2 = acc0, acc3 = acc0;

    PF_SC(X0a, X0b, W0a, W0b, s0);            // superchunk s0 -> buf0

    STAGE(0,  X0a, X0b, W0a, W0b,  X1a, X1b, W1a, W1b)
    STAGE(1,  X1a, X1b, W1a, W1b,  X0a, X0b, W0a, W0b)
    STAGE(2,  X0a, X0b, W0a, W0b,  X1a, X1b, W1a, W1b)
    STAGE(3,  X1a, X1b, W1a, W1b,  X0a, X0b, W0a, W0b)
    STAGE(4,  X0a, X0b, W0a, W0b,  X1a, X1b, W1a, W1b)
    STAGE(5,  X1a, X1b, W1a, W1b,  X0a, X0b, W0a, W0b)
    STAGE(6,  X0a, X0b, W0a, W0b,  X1a, X1b, W1a, W1b)
    STAGE(7,  X1a, X1b, W1a, W1b,  X0a, X0b, W0a, W0b)
    STAGE(8,  X0a, X0b, W0a, W0b,  X1a, X1b, W1a, W1b)
    STAGE(9,  X1a, X1b, W1a, W1b,  X0a, X0b, W0a, W0b)
    STAGE(10, X0a, X0b, W0a, W0b,  X1a, X1b, W1a, W1b)
    STAGE(11, X1a, X1b, W1a, W1b,  X0a, X0b, W0a, W0b)
    STAGE(12, X0a, X0b, W0a, W0b,  X1a, X1b, W1a, W1b)
    STAGE(13, X1a, X1b, W1a, W1b,  X0a, X0b, W0a, W0b)
    STAGE(14, X0a, X0b, W0a, W0b,  X1a, X1b, W1a, W1b)
    STAGE(15, X1a, X1b, W1a, W1b,  X0a, X0b, W0a, W0b)

    const int r0 = r4 << 2;
    out[(size_t)(r0 + 0) * 256 + c0 + lane] = fminf((float)acc0.x, (float)acc0.y);
    out[(size_t)(r0 + 1) * 256 + c0 + lane] = fminf((float)acc1.x, (float)acc1.y);
    out[(size_t)(r0 + 2) * 256 + c0 + lane] = fminf((float)acc2.x, (float)acc2.y);
    out[(size_t)(r0 + 3) * 256 + c0 + lane] = fminf((float)acc3.x, (float)acc3.y);
}

extern "C" void kernel_launch(void* const* d_in, const int* in_sizes, int n_in,
                              void* d_out, int out_size, void* d_ws, size_t ws_size,
                              hipStream_t stream) {
    const float* x = (const float*)d_in[0];
    const float* w = (const float*)d_in[1];
    float* out = (float*)d_out;

    unsigned int* xt = (unsigned int*)d_ws;                          // 2 MB
    unsigned int* wq = (unsigned int*)((char*)d_ws + (2u << 20));    // 128 KB

    hipLaunchKernelGGL(prepack_kernel, dim3(2176), dim3(256), 0, stream, x, w, xt, wq);
    hipLaunchKernelGGL(stemm_main, dim3(1024), dim3(256), 0, stream, xt, wq, out);
}

// Round 8
// 19.475 us; speedup vs baseline: 1.3480x; 1.0991x over previous
//
#include <hip/hip_runtime.h>

// out[b,o] = min_i max(x[b,i], w[i,o])  (forward value of the STE expression)
// x: [4096][256] f32, w: [256][256] f32, out: [4096][256] f32.
//
// R8: ONE fused kernel (kill the prepack dispatch + inter-node gap).
// Per block (16 rows x 64 cols, 256 thr = 4 waves, 4 blocks/CU):
//  phase0a: convert own 16 x-rows to f16 pairs -> block-private 8 KB ws slice
//  phase0b: convert own w slice (256 i x 64 cols) to f16 pairs -> 32 KB LDS
//  fence:   vmcnt(0) + barrier + s_dcache_inv (L1 is write-through -> stores
//           are in L2; K$ refetches from L2; same CU => same XCD)
//  main:    per superchunk (16 i): 2x s_load_dwordx16 (x, SGPR src0 of
//           v_pk_max_f16) + 2x ds_read_b128 (w, consecutive-16B = conflict-
//           free) + 64 fused v_pk_max/v_pk_min. Double-buffered, lgkmcnt(0)
//           waits only (SMEM retires out-of-order), wave phase-stagger.
// VALU floor: 16 sc x 128 cy x 4 waves/SIMD = 8192 cy ~= 3.4 us.

typedef _Float16 h2 __attribute__((ext_vector_type(2)));
typedef int i16v __attribute__((ext_vector_type(16)));

static __device__ __forceinline__ unsigned int cvtpk(float a, float b) {
    return __builtin_bit_cast(unsigned int, __builtin_amdgcn_cvt_pkrtz(a, b));
}

// fused pmax+pmin, SGPR src0 for the x operand
#define PKSTEP(XS, WV, ACC) do { int _t;                                     \
    asm("v_pk_max_f16 %0, %2, %3\n\t"                                        \
        "v_pk_min_f16 %1, %1, %0"                                            \
        : "=&v"(_t), "+v"(ACC) : "s"(XS), "v"(WV)); } while (0)

// one 8-i half-superchunk: X = 16 SGPRs [rr][j], W = 4 dwords [j]
#define STEPC(Xv, Wv) do {                                                   \
    PKSTEP(Xv[0],  Wv.x, acc0); PKSTEP(Xv[4],  Wv.x, acc1);                  \
    PKSTEP(Xv[8],  Wv.x, acc2); PKSTEP(Xv[12], Wv.x, acc3);                  \
    PKSTEP(Xv[1],  Wv.y, acc0); PKSTEP(Xv[5],  Wv.y, acc1);                  \
    PKSTEP(Xv[9],  Wv.y, acc2); PKSTEP(Xv[13], Wv.y, acc3);                  \
    PKSTEP(Xv[2],  Wv.z, acc0); PKSTEP(Xv[6],  Wv.z, acc1);                  \
    PKSTEP(Xv[10], Wv.z, acc2); PKSTEP(Xv[14], Wv.z, acc3);                  \
    PKSTEP(Xv[3],  Wv.w, acc0); PKSTEP(Xv[7],  Wv.w, acc1);                  \
    PKSTEP(Xv[11], Wv.w, acc2); PKSTEP(Xv[15], Wv.w, acc3); } while (0)

#define WAITL() do {                                                         \
    asm volatile("s_waitcnt lgkmcnt(0)" ::: "memory");                       \
    __builtin_amdgcn_sched_barrier(0); } while (0)

// prefetch one superchunk (16 i): 2 s_load_dwordx16 (x) + 2 ds_read_b128 (w)
#define PF_SC(XA_, XB_, WA_, WB_, SC) do {                                   \
    const unsigned long long _xs = xa + (unsigned long long)(((SC) & 15) << 7); \
    asm volatile("s_load_dwordx16 %0, %2, 0x0\n\t"                           \
                 "s_load_dwordx16 %1, %2, 0x40"                              \
                 : "=&s"(XA_), "=&s"(XB_) : "s"(_xs));                       \
    const unsigned int _wo = wob + (unsigned int)(((SC) & 15) << 11);        \
    asm volatile("ds_read_b128 %0, %2\n\t"                                   \
                 "ds_read_b128 %1, %2 offset:1024"                           \
                 : "=&v"(WA_), "=&v"(WB_) : "v"(_wo)); } while (0)

#define STAGE(K, CXA, CXB, CWA, CWB, NXA, NXB, NWA, NWB)                     \
    WAITL();                                                                 \
    if ((K) < 15) PF_SC(NXA, NXB, NWA, NWB, s0 + (K) + 1);                   \
    STEPC(CXA, CWA); STEPC(CXB, CWB);

__global__ __launch_bounds__(256, 4)
void stemm_fused(const float* __restrict__ x, const float* __restrict__ w,
                 float* __restrict__ out, unsigned int* __restrict__ wsx) {
    __shared__ __align__(16) unsigned char wlds[32768];
    const int t    = threadIdx.x;
    const int lane = t & 63;
    const int wv   = __builtin_amdgcn_readfirstlane(t >> 6);   // wave 0..3
    const int c0   = (blockIdx.x & 3) << 6;                    // col group
    const int rb   = blockIdx.x >> 2;                          // row block
    const int r0   = rb << 4;                                  // 16 rows/block
    unsigned int* xws = wsx + ((size_t)blockIdx.x << 11);      // 8 KB private

    // ---- phase 0a: x rows -> f16 pairs -> ws (layout [wv][sc][half][rr][j]) ----
    {
        const int row = t >> 4, iq = t & 15;
        const float4* xp = reinterpret_cast<const float4*>(&x[(size_t)(r0 + row) * 256 + (iq << 4)]);
        const float4 a = xp[0], b = xp[1], c = xp[2], d = xp[3];
        uint4 h0 = { cvtpk(a.x,a.y), cvtpk(a.z,a.w), cvtpk(b.x,b.y), cvtpk(b.z,b.w) };
        uint4 h1 = { cvtpk(c.x,c.y), cvtpk(c.z,c.w), cvtpk(d.x,d.y), cvtpk(d.z,d.w) };
        const int base = ((row >> 2) << 9) + (iq << 5) + ((row & 3) << 2);   // u32 units
        *reinterpret_cast<uint4*>(xws + base)      = h0;
        *reinterpret_cast<uint4*>(xws + base + 16) = h1;
    }

    // ---- phase 0b: w slice -> f16 pairs -> LDS ([sc][k][col] 16B chunks) ----
#pragma unroll
    for (int uu = 0; uu < 4; ++uu) {
        const int u    = (uu << 8) + t;
        const int colp = u & 31;            // col pair
        const int k    = (u >> 5) & 1;      // half (pairs 0-3 / 4-7)
        const int sc   = u >> 6;            // superchunk
        const int i0   = (sc << 4) + (k << 3);
        float2 v[8];
#pragma unroll
        for (int e = 0; e < 8; ++e)
            v[e] = *reinterpret_cast<const float2*>(&w[(size_t)(i0 + e) * 256 + c0 + (colp << 1)]);
        uint4 qa = { cvtpk(v[0].x,v[1].x), cvtpk(v[2].x,v[3].x), cvtpk(v[4].x,v[5].x), cvtpk(v[6].x,v[7].x) };
        uint4 qb = { cvtpk(v[0].y,v[1].y), cvtpk(v[2].y,v[3].y), cvtpk(v[4].y,v[5].y), cvtpk(v[6].y,v[7].y) };
        unsigned char* p = wlds + (sc << 11) + (k << 10) + (colp << 5);
        *reinterpret_cast<uint4*>(p)      = qa;       // col 2*colp
        *reinterpret_cast<uint4*>(p + 16) = qb;       // col 2*colp+1
    }

    // ---- fence: stores -> L2, all waves done, drop stale K$ lines ----
    asm volatile("s_waitcnt vmcnt(0) lgkmcnt(0)" ::: "memory");
    __syncthreads();
    asm volatile("s_dcache_inv\n\ts_nop 3" ::: "memory");
    __builtin_amdgcn_sched_barrier(0);

    // ---- main loop ----
    const unsigned long long xa = (unsigned long long)xws + ((unsigned long long)wv << 11);
    const unsigned int wob = (unsigned int)(unsigned long long)(wlds) + (unsigned int)(lane << 4);
    const int s0 = wv << 2;                                    // phase stagger

    i16v X0a{}, X0b{}, X1a{}, X1b{};
    uint4 W0a{0,0,0,0}, W0b{0,0,0,0}, W1a{0,0,0,0}, W1b{0,0,0,0};

    h2 acc0 = h2{(_Float16)65504.0f, (_Float16)65504.0f};
    h2 acc1 = acc0, acc2 = acc0, acc3 = acc0;

    PF_SC(X0a, X0b, W0a, W0b, s0);

    STAGE(0,  X0a, X0b, W0a, W0b,  X1a, X1b, W1a, W1b)
    STAGE(1,  X1a, X1b, W1a, W1b,  X0a, X0b, W0a, W0b)
    STAGE(2,  X0a, X0b, W0a, W0b,  X1a, X1b, W1a, W1b)
    STAGE(3,  X1a, X1b, W1a, W1b,  X0a, X0b, W0a, W0b)
    STAGE(4,  X0a, X0b, W0a, W0b,  X1a, X1b, W1a, W1b)
    STAGE(5,  X1a, X1b, W1a, W1b,  X0a, X0b, W0a, W0b)
    STAGE(6,  X0a, X0b, W0a, W0b,  X1a, X1b, W1a, W1b)
    STAGE(7,  X1a, X1b, W1a, W1b,  X0a, X0b, W0a, W0b)
    STAGE(8,  X0a, X0b, W0a, W0b,  X1a, X1b, W1a, W1b)
    STAGE(9,  X1a, X1b, W1a, W1b,  X0a, X0b, W0a, W0b)
    STAGE(10, X0a, X0b, W0a, W0b,  X1a, X1b, W1a, W1b)
    STAGE(11, X1a, X1b, W1a, W1b,  X0a, X0b, W0a, W0b)
    STAGE(12, X0a, X0b, W0a, W0b,  X1a, X1b, W1a, W1b)
    STAGE(13, X1a, X1b, W1a, W1b,  X0a, X0b, W0a, W0b)
    STAGE(14, X0a, X0b, W0a, W0b,  X1a, X1b, W1a, W1b)
    STAGE(15, X1a, X1b, W1a, W1b,  X0a, X0b, W0a, W0b)

    const int orow = r0 + (wv << 2);
    out[(size_t)(orow + 0) * 256 + c0 + lane] = fminf((float)acc0.x, (float)acc0.y);
    out[(size_t)(orow + 1) * 256 + c0 + lane] = fminf((float)acc1.x, (float)acc1.y);
    out[(size_t)(orow + 2) * 256 + c0 + lane] = fminf((float)acc2.x, (float)acc2.y);
    out[(size_t)(orow + 3) * 256 + c0 + lane] = fminf((float)acc3.x, (float)acc3.y);
}

extern "C" void kernel_launch(void* const* d_in, const int* in_sizes, int n_in,
                              void* d_out, int out_size, void* d_ws, size_t ws_size,
                              hipStream_t stream) {
    const float* x = (const float*)d_in[0];
    const float* w = (const float*)d_in[1];
    float* out = (float*)d_out;
    unsigned int* wsx = (unsigned int*)d_ws;     // 1024 blocks x 8 KB = 8 MB

    hipLaunchKernelGGL(stemm_fused, dim3(1024), dim3(256), 0, stream, x, w, out, wsx);
}

// Round 9
// 19.110 us; speedup vs baseline: 1.3737x; 1.0191x over previous
//
#include <hip/hip_runtime.h>

// out[b,o] = min_i max(x[b,i], w[i,o])  (forward value of the STE expression)
// x: [4096][256] f32, w: [256][256] f32, out: [4096][256] f32.
//
// R9 = R8 with taller blocks: 256 blocks x 1024 thr (16 waves), each block
// 64 rows x 64 cols, 1 block/CU, 4 waves/SIMD. w f32 L2 re-read drops 4x
// (64 MB -> 16 MB). Per-wave main loop identical to R8:
//   x (wave-uniform) on the SCALAR pipe: s_load_dwordx16 from a block-private
//   f16-packed ws slice (written in phase 0, K$ invalidated after fence);
//   w per-lane from 32 KB LDS via ds_read_b128 (consecutive 16B, no conflict);
//   fused v_pk_max_f16 (SGPR src0) + v_pk_min_f16; double-buffered superchunks
//   (16 i); lgkmcnt(0)-only waits; per-wave phase stagger s0 = wv.
// VALU floor: 512 PKSTEP/thread = 1024 instr = 2048 cy/wave; 4 waves/SIMD
// -> 8192 cy ~= 3.4 us.

typedef _Float16 h2 __attribute__((ext_vector_type(2)));
typedef int i16v __attribute__((ext_vector_type(16)));

static __device__ __forceinline__ unsigned int cvtpk(float a, float b) {
    return __builtin_bit_cast(unsigned int, __builtin_amdgcn_cvt_pkrtz(a, b));
}

// fused pmax+pmin, SGPR src0 for the x operand
#define PKSTEP(XS, WV, ACC) do { int _t;                                     \
    asm("v_pk_max_f16 %0, %2, %3\n\t"                                        \
        "v_pk_min_f16 %1, %1, %0"                                            \
        : "=&v"(_t), "+v"(ACC) : "s"(XS), "v"(WV)); } while (0)

// one 8-i half-superchunk: X = 16 SGPRs [rr][j], W = 4 dwords [j]
#define STEPC(Xv, Wv) do {                                                   \
    PKSTEP(Xv[0],  Wv.x, acc0); PKSTEP(Xv[4],  Wv.x, acc1);                  \
    PKSTEP(Xv[8],  Wv.x, acc2); PKSTEP(Xv[12], Wv.x, acc3);                  \
    PKSTEP(Xv[1],  Wv.y, acc0); PKSTEP(Xv[5],  Wv.y, acc1);                  \
    PKSTEP(Xv[9],  Wv.y, acc2); PKSTEP(Xv[13], Wv.y, acc3);                  \
    PKSTEP(Xv[2],  Wv.z, acc0); PKSTEP(Xv[6],  Wv.z, acc1);                  \
    PKSTEP(Xv[10], Wv.z, acc2); PKSTEP(Xv[14], Wv.z, acc3);                  \
    PKSTEP(Xv[3],  Wv.w, acc0); PKSTEP(Xv[7],  Wv.w, acc1);                  \
    PKSTEP(Xv[11], Wv.w, acc2); PKSTEP(Xv[15], Wv.w, acc3); } while (0)

#define WAITL() do {                                                         \
    asm volatile("s_waitcnt lgkmcnt(0)" ::: "memory");                       \
    __builtin_amdgcn_sched_barrier(0); } while (0)

// prefetch one superchunk (16 i): 2 s_load_dwordx16 (x) + 2 ds_read_b128 (w)
#define PF_SC(XA_, XB_, WA_, WB_, SC) do {                                   \
    const unsigned long long _xs = xa + (unsigned long long)(((SC) & 15) << 7); \
    asm volatile("s_load_dwordx16 %0, %2, 0x0\n\t"                           \
                 "s_load_dwordx16 %1, %2, 0x40"                              \
                 : "=&s"(XA_), "=&s"(XB_) : "s"(_xs));                       \
    const unsigned int _wo = wob + (unsigned int)(((SC) & 15) << 11);        \
    asm volatile("ds_read_b128 %0, %2\n\t"                                   \
                 "ds_read_b128 %1, %2 offset:1024"                           \
                 : "=&v"(WA_), "=&v"(WB_) : "v"(_wo)); } while (0)

#define STAGE(K, CXA, CXB, CWA, CWB, NXA, NXB, NWA, NWB)                     \
    WAITL();                                                                 \
    if ((K) < 15) PF_SC(NXA, NXB, NWA, NWB, s0 + (K) + 1);                   \
    STEPC(CXA, CWA); STEPC(CXB, CWB);

__global__ __launch_bounds__(1024, 4)
void stemm_fused(const float* __restrict__ x, const float* __restrict__ w,
                 float* __restrict__ out, unsigned int* __restrict__ wsx) {
    __shared__ __align__(16) unsigned char wlds[32768];
    const int t    = threadIdx.x;
    const int lane = t & 63;
    const int wv   = __builtin_amdgcn_readfirstlane(t >> 6);   // wave 0..15
    const int c0   = (blockIdx.x & 3) << 6;                    // col group
    const int rb   = blockIdx.x >> 2;                          // row block
    const int r0   = rb << 6;                                  // 64 rows/block
    unsigned int* xws = wsx + ((size_t)blockIdx.x << 13);      // 32 KB private

    // ---- phase 0a: 64 x-rows -> f16 pairs -> ws ([wv][sc][half][rr][j]) ----
    {
        const int row = t >> 4, iq = t & 15;                   // row 0..63, sc 0..15
        const float4* xp = reinterpret_cast<const float4*>(&x[(size_t)(r0 + row) * 256 + (iq << 4)]);
        const float4 a = xp[0], b = xp[1], c = xp[2], d = xp[3];
        uint4 h0 = { cvtpk(a.x,a.y), cvtpk(a.z,a.w), cvtpk(b.x,b.y), cvtpk(b.z,b.w) };
        uint4 h1 = { cvtpk(c.x,c.y), cvtpk(c.z,c.w), cvtpk(d.x,d.y), cvtpk(d.z,d.w) };
        const int base = ((row >> 2) << 9) + (iq << 5) + ((row & 3) << 2);   // u32 units
        *reinterpret_cast<uint4*>(xws + base)      = h0;       // pairs j0..3
        *reinterpret_cast<uint4*>(xws + base + 16) = h1;       // pairs j4..7
    }

    // ---- phase 0b: w slice (256 i x 64 cols) -> f16 pairs -> LDS, one pass ----
    {
        const int colp = t & 31;            // col pair
        const int k    = (t >> 5) & 1;      // half (pairs 0-3 / 4-7)
        const int sc   = t >> 6;            // superchunk 0..15
        const int i0   = (sc << 4) + (k << 3);
        float2 v[8];
#pragma unroll
        for (int e = 0; e < 8; ++e)
            v[e] = *reinterpret_cast<const float2*>(&w[(size_t)(i0 + e) * 256 + c0 + (colp << 1)]);
        uint4 qa = { cvtpk(v[0].x,v[1].x), cvtpk(v[2].x,v[3].x), cvtpk(v[4].x,v[5].x), cvtpk(v[6].x,v[7].x) };
        uint4 qb = { cvtpk(v[0].y,v[1].y), cvtpk(v[2].y,v[3].y), cvtpk(v[4].y,v[5].y), cvtpk(v[6].y,v[7].y) };
        unsigned char* p = wlds + (sc << 11) + (k << 10) + (colp << 5);
        *reinterpret_cast<uint4*>(p)      = qa;       // col 2*colp
        *reinterpret_cast<uint4*>(p + 16) = qb;       // col 2*colp+1
    }

    // ---- fence: stores -> L2, all waves done, drop stale K$ lines ----
    asm volatile("s_waitcnt vmcnt(0) lgkmcnt(0)" ::: "memory");
    __syncthreads();
    asm volatile("s_dcache_inv\n\ts_nop 3" ::: "memory");
    __builtin_amdgcn_sched_barrier(0);

    // ---- main loop ----
    const unsigned long long xa = (unsigned long long)xws + ((unsigned long long)wv << 11);
    const unsigned int wob = (unsigned int)(unsigned long long)(wlds) + (unsigned int)(lane << 4);
    const int s0 = wv;                                         // phase stagger

    i16v X0a{}, X0b{}, X1a{}, X1b{};
    uint4 W0a{0,0,0,0}, W0b{0,0,0,0}, W1a{0,0,0,0}, W1b{0,0,0,0};

    h2 acc0 = h2{(_Float16)65504.0f, (_Float16)65504.0f};
    h2 acc1 = acc0, acc2 = acc0, acc3 = acc0;

    PF_SC(X0a, X0b, W0a, W0b, s0);

    STAGE(0,  X0a, X0b, W0a, W0b,  X1a, X1b, W1a, W1b)
    STAGE(1,  X1a, X1b, W1a, W1b,  X0a, X0b, W0a, W0b)
    STAGE(2,  X0a, X0b, W0a, W0b,  X1a, X1b, W1a, W1b)
    STAGE(3,  X1a, X1b, W1a, W1b,  X0a, X0b, W0a, W0b)
    STAGE(4,  X0a, X0b, W0a, W0b,  X1a, X1b, W1a, W1b)
    STAGE(5,  X1a, X1b, W1a, W1b,  X0a, X0b, W0a, W0b)
    STAGE(6,  X0a, X0b, W0a, W0b,  X1a, X1b, W1a, W1b)
    STAGE(7,  X1a, X1b, W1a, W1b,  X0a, X0b, W0a, W0b)
    STAGE(8,  X0a, X0b, W0a, W0b,  X1a, X1b, W1a, W1b)
    STAGE(9,  X1a, X1b, W1a, W1b,  X0a, X0b, W0a, W0b)
    STAGE(10, X0a, X0b, W0a, W0b,  X1a, X1b, W1a, W1b)
    STAGE(11, X1a, X1b, W1a, W1b,  X0a, X0b, W0a, W0b)
    STAGE(12, X0a, X0b, W0a, W0b,  X1a, X1b, W1a, W1b)
    STAGE(13, X1a, X1b, W1a, W1b,  X0a, X0b, W0a, W0b)
    STAGE(14, X0a, X0b, W0a, W0b,  X1a, X1b, W1a, W1b)
    STAGE(15, X1a, X1b, W1a, W1b,  X0a, X0b, W0a, W0b)

    const int orow = r0 + (wv << 2);
    out[(size_t)(orow + 0) * 256 + c0 + lane] = fminf((float)acc0.x, (float)acc0.y);
    out[(size_t)(orow + 1) * 256 + c0 + lane] = fminf((float)acc1.x, (float)acc1.y);
    out[(size_t)(orow + 2) * 256 + c0 + lane] = fminf((float)acc2.x, (float)acc2.y);
    out[(size_t)(orow + 3) * 256 + c0 + lane] = fminf((float)acc3.x, (float)acc3.y);
}

extern "C" void kernel_launch(void* const* d_in, const int* in_sizes, int n_in,
                              void* d_out, int out_size, void* d_ws, size_t ws_size,
                              hipStream_t stream) {
    const float* x = (const float*)d_in[0];
    const float* w = (const float*)d_in[1];
    float* out = (float*)d_out;
    unsigned int* wsx = (unsigned int*)d_ws;     // 256 blocks x 32 KB = 8 MB

    hipLaunchKernelGGL(stemm_fused, dim3(256), dim3(1024), 0, stream, x, w, out, wsx);
}